// Round 2
// baseline (775.969 us; speedup 1.0000x reference)
//
#include <hip/hip_runtime.h>
#include <math.h>

constexpr int BATCH = 4;
constexpr int SEQ   = 2048;
constexpr int HID   = 2048;
constexpr int NHEAD = 8;
constexpr int HD    = 256;
constexpr int QKVN  = (NHEAD + 2) * HD;          // 2560
constexpr float SCL = 0.0625f;                   // 256^-0.5

typedef __bf16 bf16_t;
typedef __bf16 bf16x8 __attribute__((ext_vector_type(8)));
typedef float  f32x4  __attribute__((ext_vector_type(4)));

__device__ __forceinline__ f32x4 zero4() {
  f32x4 z; z[0] = 0.f; z[1] = 0.f; z[2] = 0.f; z[3] = 0.f; return z;
}

__device__ __forceinline__ f32x4 mfma16(bf16x8 a, bf16x8 b, f32x4 c) {
  return __builtin_amdgcn_mfma_f32_16x16x32_bf16(a, b, c, 0, 0, 0);
}

// async global->LDS, 16B per lane. lds must be wave-uniform base; HW adds lane*16.
__device__ __forceinline__ void gl2lds16(const void* g, void* lds) {
  typedef __attribute__((address_space(1))) void* gp_t;
  typedef __attribute__((address_space(3))) void* lp_t;
  __builtin_amdgcn_global_load_lds((gp_t)(size_t)g,
                                   (lp_t)(unsigned int)(size_t)lds, 16, 0, 0);
}

__device__ __forceinline__ float rmax16(float v) {
#pragma unroll
  for (int o = 1; o < 16; o <<= 1) v = fmaxf(v, __shfl_xor(v, o));
  return v;
}
__device__ __forceinline__ float rsum16(float v) {
#pragma unroll
  for (int o = 1; o < 16; o <<= 1) v += __shfl_xor(v, o);
  return v;
}

// ---------- fp32 -> bf16 bulk convert (8 elems/thread) ----------
__global__ __launch_bounds__(256)
void cvt_bf16_kernel(const float* __restrict__ in, bf16_t* __restrict__ out) {
  const int i = blockIdx.x * 256 + threadIdx.x;
  const float4 a = ((const float4*)in)[i * 2];
  const float4 b = ((const float4*)in)[i * 2 + 1];
  bf16x8 o;
  o[0] = (bf16_t)a.x; o[1] = (bf16_t)a.y; o[2] = (bf16_t)a.z; o[3] = (bf16_t)a.w;
  o[4] = (bf16_t)b.x; o[5] = (bf16_t)b.y; o[6] = (bf16_t)b.z; o[7] = (bf16_t)b.w;
  ((bf16x8*)out)[i] = o;
}

// ---------- w[K][N] fp32 -> wT[N][K] bf16, 64x64 tiles ----------
__global__ __launch_bounds__(256)
void transw_kernel(const float* __restrict__ w, bf16_t* __restrict__ wT, int K, int N) {
  __shared__ __align__(16) bf16_t tile[64][72];
  const int n0 = blockIdx.x * 64, k0 = blockIdx.y * 64;
  const int t = threadIdx.x, rr = t >> 3, c8 = (t & 7) * 8;
#pragma unroll
  for (int it = 0; it < 2; ++it) {
    const int r = rr + it * 32;
    const float4* p = (const float4*)(w + (size_t)(k0 + r) * N + n0 + c8);
    const float4 a = p[0], b = p[1];
    bf16x8 o;
    o[0] = (bf16_t)a.x; o[1] = (bf16_t)a.y; o[2] = (bf16_t)a.z; o[3] = (bf16_t)a.w;
    o[4] = (bf16_t)b.x; o[5] = (bf16_t)b.y; o[6] = (bf16_t)b.z; o[7] = (bf16_t)b.w;
    *(bf16x8*)&tile[r][c8] = o;
  }
  __syncthreads();
#pragma unroll
  for (int it = 0; it < 2; ++it) {
    const int rn = rr + it * 32;
    bf16x8 o;
#pragma unroll
    for (int j = 0; j < 8; ++j) o[j] = tile[c8 + j][rn];
    *(bf16x8*)&wT[(size_t)(n0 + rn) * K + k0 + c8] = o;
  }
}

// ---------- MFMA GEMM: C[M][N] = A[M][K] * BT[N][K]^T  (m97 recipe + T1) ----------
template <typename TC>
__global__ __launch_bounds__(256)
void gemm_bt_kernel(const bf16_t* __restrict__ A, const bf16_t* __restrict__ BT,
                    TC* __restrict__ C, int M, int N, int K) {
  __shared__ __align__(16) bf16_t As[128 * 32];
  __shared__ __align__(16) bf16_t Bs[128 * 32];
  const int tid = threadIdx.x;
  const int lane = tid & 63, w = tid >> 6;
  const int quad = lane >> 4, l15 = lane & 15;

  // T1: XCD-aware bijective swizzle (grids are multiples of 8)
  const int nwg = gridDim.x * gridDim.y;
  const int flat = blockIdx.y * gridDim.x + blockIdx.x;
  const int cpx = nwg >> 3;
  const int swz = (flat & 7) * cpx + (flat >> 3);
  const int bm = (swz / gridDim.x) * 128, bn = (swz % gridDim.x) * 128;

  const int wm = (w & 1) * 64, wn = (w >> 1) * 64;
  const int r0 = tid >> 2, c0 = tid & 3;   // staging: 4 chunks of 16B per 32-elem row

  f32x4 acc[4][4];
#pragma unroll
  for (int mt = 0; mt < 4; ++mt)
#pragma unroll
    for (int nt = 0; nt < 4; ++nt) acc[mt][nt] = zero4();

  for (int k0 = 0; k0 < K; k0 += 32) {
#pragma unroll
    for (int i = 0; i < 2; ++i) {
      const int r = r0 + i * 64;
      const int cg = (c0 ^ (r & 3)) << 3;   // XOR-swizzled source column
      gl2lds16(A + (size_t)(bm + r) * K + k0 + cg, &As[(i * 256 + w * 64) * 8]);
      gl2lds16(BT + (size_t)(bn + r) * K + k0 + cg, &Bs[(i * 256 + w * 64) * 8]);
    }
    __syncthreads();
    bf16x8 af[4], bf[4];
#pragma unroll
    for (int mt = 0; mt < 4; ++mt) {
      const int row = wm + mt * 16 + l15;
      af[mt] = *(const bf16x8*)&As[row * 32 + ((quad ^ (row & 3)) << 3)];
    }
#pragma unroll
    for (int nt = 0; nt < 4; ++nt) {
      const int row = wn + nt * 16 + l15;
      bf[nt] = *(const bf16x8*)&Bs[row * 32 + ((quad ^ (row & 3)) << 3)];
    }
#pragma unroll
    for (int mt = 0; mt < 4; ++mt)
#pragma unroll
      for (int nt = 0; nt < 4; ++nt)
        acc[mt][nt] = mfma16(af[mt], bf[nt], acc[mt][nt]);
    __syncthreads();
  }

#pragma unroll
  for (int mt = 0; mt < 4; ++mt)
#pragma unroll
    for (int nt = 0; nt < 4; ++nt)
#pragma unroll
      for (int r = 0; r < 4; ++r) {
        const int row = bm + wm + mt * 16 + quad * 4 + r;
        const int col = bn + wn + nt * 16 + l15;
        C[(size_t)row * N + col] = (TC)acc[mt][nt][r];
      }
}

// ---------- RoPE cos/sin table: tab[s][i] = (cos, sin) ----------
__global__ __launch_bounds__(128)
void rope_table_kernel(const int* __restrict__ pos, float2* __restrict__ tab) {
  const int s = blockIdx.x, i = threadIdx.x;
  const float inv_freq = powf(10000.0f, -(float)i / 128.0f);
  const float ang = (float)pos[s] * inv_freq;
  float sn, cs;
  sincosf(ang, &sn, &cs);
  tab[s * 128 + i] = make_float2(cs, sn);
}

// ---------- RoPE apply, table-driven, bf16x8 vectorized ----------
__global__ __launch_bounds__(256)
void rope_kernel(const float2* __restrict__ tab, bf16_t* __restrict__ qkv) {
  const int bs = blockIdx.x * 16 + (threadIdx.x >> 4);
  const int h  = blockIdx.y;
  const int i0 = (threadIdx.x & 15) * 8;
  const int s  = bs & (SEQ - 1);
  const size_t base = (size_t)bs * QKVN + (size_t)h * HD;
  bf16x8 a = *(const bf16x8*)&qkv[base + i0];
  bf16x8 b = *(const bf16x8*)&qkv[base + 128 + i0];
  bf16x8 oa, ob;
#pragma unroll
  for (int j = 0; j < 8; ++j) {
    const float2 t = tab[s * 128 + i0 + j];
    const float x1 = (float)a[j], x2 = (float)b[j];
    oa[j] = (bf16_t)(x1 * t.x - x2 * t.y);
    ob[j] = (bf16_t)(x2 * t.x + x1 * t.y);
  }
  *(bf16x8*)&qkv[base + i0]       = oa;
  *(bf16x8*)&qkv[base + 128 + i0] = ob;
}

// ---------- V transpose: qkv v-part [s][d] -> Vt[b][d][s] ----------
__global__ __launch_bounds__(256)
void vtrans_kernel(const bf16_t* __restrict__ qkv, bf16_t* __restrict__ Vt) {
  __shared__ __align__(16) bf16_t tile[64][72];
  const int s0 = blockIdx.x * 64, d0 = blockIdx.y * 64, b = blockIdx.z;
  const int t = threadIdx.x, rr = t >> 3, c8 = (t & 7) * 8;
#pragma unroll
  for (int it = 0; it < 2; ++it) {
    const int r = rr + it * 32;
    *(bf16x8*)&tile[r][c8] =
        *(const bf16x8*)&qkv[(size_t)(b * SEQ + s0 + r) * QKVN + 2304 + d0 + c8];
  }
  __syncthreads();
#pragma unroll
  for (int it = 0; it < 2; ++it) {
    const int dd = rr + it * 32;
    bf16x8 o;
#pragma unroll
    for (int j = 0; j < 8; ++j) o[j] = tile[c8 + j][dd];
    *(bf16x8*)&Vt[(size_t)(b * HD + d0 + dd) * SEQ + s0 + c8] = o;
  }
}

// ---------- flash attention: 4 waves = 4 heads, 32 q-rows per wave ----------
// Each K/V-frag LDS read feeds 2 MFMAs (2 q-subtiles) -> LDS read traffic per
// unit work halved vs 16-q version (attn was LDS-read-BW-bound).
// LDS = 32K (K) + 32K (Vt) + 16K (P, XOR-swizzled) = 80 KB -> 2 blocks/CU;
// cross-block overlap hides stage latency (m97 mechanism), no double-buffer.
// Grid 512 = 4 batches x 64 q-groups x 2 head-halves; block i and i+256 have
// complementary q-groups so co-resident blocks sum to ~33 K-tiles.
__global__ __launch_bounds__(256, 2)
void attn_kernel(const bf16_t* __restrict__ qkv, const bf16_t* __restrict__ Vt,
                 bf16_t* __restrict__ O) {
  __shared__ __align__(16) bf16_t Ks[64 * 256];     // [key][d], chunk-swizzled (32 KB)
  __shared__ __align__(16) bf16_t Vts[256 * 64];    // [d][key], chunk-swizzled (32 KB)
  __shared__ __align__(16) bf16_t Pl[4][32][64];    // per-wave P, chunk-XOR (16 KB)

  const int tid = threadIdx.x, w = tid >> 6, lane = tid & 63;
  const int quad = lane >> 4, l15 = lane & 15;
  const int bid = blockIdx.x;
  const int j = bid & 255;
  const int b = j >> 6;
  const int hg = bid >> 8;
  const int qg = hg ? (63 - (j & 63)) : (j & 63);
  const int h = hg * 4 + w;
  const int q0 = qg * 32;
  const int ntiles = (q0 + 31) / 64 + 1;

  // staging decomposition (256 threads, 8 iters each for K and V)
  const int krow_base = w * 2 + (lane >> 5);   // +i*8  -> key row 0..63
  const int kcol = lane & 31;                  // 16B chunk within 256-d row
  const int vrow_base = w * 8 + (lane >> 3);   // +i*32 -> d row 0..255
  const int vcol = lane & 7;                   // 16B chunk within 64-key row

  const bf16_t* kbase0 = qkv + (size_t)(b * SEQ) * QKVN + 2048;
  const bf16_t* vbase0 = Vt + (size_t)b * HD * SEQ;

  // Q fragments: 2 q-subtiles x 8 ksteps (A-layout: m=l15, k=quad*8+j)
  bf16x8 qf[2][8];
#pragma unroll
  for (int sub = 0; sub < 2; ++sub) {
    const bf16_t* qp = qkv + (size_t)(b * SEQ + q0 + sub * 16 + l15) * QKVN +
                       (size_t)h * HD + quad * 8;
#pragma unroll
    for (int ks = 0; ks < 8; ++ks) qf[sub][ks] = *(const bf16x8*)(qp + ks * 32);
  }

  float mrun[2][4], lrun[2][4];
  f32x4 of[2][16];
#pragma unroll
  for (int sub = 0; sub < 2; ++sub) {
#pragma unroll
    for (int r = 0; r < 4; ++r) { mrun[sub][r] = -3e38f; lrun[sub][r] = 0.f; }
#pragma unroll
    for (int dt = 0; dt < 16; ++dt) of[sub][dt] = zero4();
  }

  for (int kt = 0; kt < ntiles; ++kt) {
    // ---- stage K (64x256) + Vt (256x64) cooperatively ----
    const bf16_t* kbase = kbase0 + (size_t)(kt * 64) * QKVN;
#pragma unroll
    for (int i = 0; i < 8; ++i) {
      const int r = i * 8 + krow_base;
      gl2lds16(kbase + (size_t)r * QKVN + ((kcol ^ (r & 31)) << 3),
               &Ks[(i * 256 + w * 64) * 8]);
    }
    const bf16_t* vbase = vbase0 + kt * 64;
#pragma unroll
    for (int i = 0; i < 8; ++i) {
      const int r = i * 32 + vrow_base;
      gl2lds16(vbase + (size_t)r * SEQ + ((vcol ^ (r & 7)) << 3),
               &Vts[(i * 256 + w * 64) * 8]);
    }
    __syncthreads();

    // ---- S = Q K^T, both q-subtiles share each K-frag read ----
    f32x4 sf[2][4];
#pragma unroll
    for (int nt = 0; nt < 4; ++nt) {
      f32x4 a0 = zero4(), a1 = zero4();
      const int row = nt * 16 + l15;
#pragma unroll
      for (int ks = 0; ks < 8; ++ks) {
        const bf16x8 kf =
            *(const bf16x8*)&Ks[row * 256 + (((ks * 4 + quad) ^ (row & 31)) << 3)];
        a0 = mfma16(qf[0][ks], kf, a0);
        a1 = mfma16(qf[1][ks], kf, a1);
      }
      sf[0][nt] = a0; sf[1][nt] = a1;
    }

    // ---- scale + (diagonal-tile-only) causal mask + row max ----
    const bool lastTile = (kt == ntiles - 1);
    float mx[2][4];
#pragma unroll
    for (int sub = 0; sub < 2; ++sub)
#pragma unroll
      for (int r = 0; r < 4; ++r) {
        const int qrow = q0 + sub * 16 + quad * 4 + r;
        float v = -3e38f;
#pragma unroll
        for (int nt = 0; nt < 4; ++nt) {
          float s = sf[sub][nt][r] * SCL;
          if (lastTile) {
            const int kg = kt * 64 + nt * 16 + l15;
            if (kg > qrow) s = -3e38f;
          }
          sf[sub][nt][r] = s;
          v = fmaxf(v, s);
        }
        mx[sub][r] = rmax16(v);
      }

    // ---- defer-max (T13): rescale only when max grew by > 8 ----
    float g = 0.f;
#pragma unroll
    for (int sub = 0; sub < 2; ++sub)
#pragma unroll
      for (int r = 0; r < 4; ++r) g = fmaxf(g, mx[sub][r] - mrun[sub][r]);
    const bool resc = !__all(g <= 8.0f);
    f32x4 av[2];
    if (resc) {
#pragma unroll
      for (int sub = 0; sub < 2; ++sub)
#pragma unroll
        for (int r = 0; r < 4; ++r) {
          const float mn = fmaxf(mrun[sub][r], mx[sub][r]);
          av[sub][r] = __expf(mrun[sub][r] - mn);
          mrun[sub][r] = mn;
          lrun[sub][r] *= av[sub][r];
        }
    }

    // ---- P = exp(S - m) into swizzled Pl, row sums ----
#pragma unroll
    for (int sub = 0; sub < 2; ++sub)
#pragma unroll
      for (int r = 0; r < 4; ++r) {
        const int rowp = sub * 16 + quad * 4 + r;
        float sum = 0.f;
#pragma unroll
        for (int nt = 0; nt < 4; ++nt) {
          const float pv = __expf(sf[sub][nt][r] - mrun[sub][r]);
          Pl[w][rowp][(((nt * 2 + (l15 >> 3)) ^ (rowp & 7)) << 3) + (l15 & 7)] =
              (bf16_t)pv;
          sum += pv;
        }
        lrun[sub][r] += rsum16(sum);
      }
    if (resc) {
#pragma unroll
      for (int sub = 0; sub < 2; ++sub)
#pragma unroll
        for (int dt = 0; dt < 16; ++dt) of[sub][dt] *= av[sub];
    }
    __asm__ volatile("s_waitcnt lgkmcnt(0)" ::: "memory");  // wave-local P handoff

    // ---- O += P V, both subtiles share each V-frag read ----
    bf16x8 pa[2][2];
#pragma unroll
    for (int sub = 0; sub < 2; ++sub)
#pragma unroll
      for (int k2 = 0; k2 < 2; ++k2)
        pa[sub][k2] = *(const bf16x8*)
            &Pl[w][sub * 16 + l15][(((k2 * 4 + quad) ^ (l15 & 7)) << 3)];
#pragma unroll
    for (int dt = 0; dt < 16; ++dt) {
      const int row = dt * 16 + l15;
#pragma unroll
      for (int k2 = 0; k2 < 2; ++k2) {
        const bf16x8 vf =
            *(const bf16x8*)&Vts[row * 64 + (((k2 * 4 + quad) ^ (row & 7)) << 3)];
        of[0][dt] = mfma16(pa[0][k2], vf, of[0][dt]);
        of[1][dt] = mfma16(pa[1][k2], vf, of[1][dt]);
      }
    }

    __syncthreads();   // all reads of Ks/Vts done before next stage overwrites
  }

  // ---- epilogue: O /= l, store bf16 [b][s][h*HD+d] ----
#pragma unroll
  for (int sub = 0; sub < 2; ++sub) {
    f32x4 iv;
#pragma unroll
    for (int r = 0; r < 4; ++r) iv[r] = 1.0f / lrun[sub][r];
#pragma unroll
    for (int dt = 0; dt < 16; ++dt) {
      const f32x4 o = of[sub][dt] * iv;
#pragma unroll
      for (int r = 0; r < 4; ++r)
        O[(size_t)(b * SEQ + q0 + sub * 16 + quad * 4 + r) * HID +
          (size_t)h * HD + dt * 16 + l15] = (bf16_t)o[r];
    }
  }
}

// ---------- launch ----------
extern "C" void kernel_launch(void* const* d_in, const int* in_sizes, int n_in,
                              void* d_out, int out_size, void* d_ws, size_t ws_size,
                              hipStream_t stream) {
  const float* hidden  = (const float*)d_in[0];
  const int* positions = (const int*)d_in[1];
  const float* w_qkv   = (const float*)d_in[2];
  const float* w_o     = (const float*)d_in[3];
  float* out           = (float*)d_out;

  char* ws = (char*)d_ws;
  bf16_t* hiddenB = (bf16_t*)ws; ws += (size_t)8192 * 2048 * 2;   // 33.5 MB
  bf16_t* wqkvT   = (bf16_t*)ws; ws += (size_t)2560 * 2048 * 2;   // 10.5 MB
  bf16_t* woT     = (bf16_t*)ws; ws += (size_t)2048 * 2048 * 2;   //  8.4 MB
  bf16_t* qkvB    = (bf16_t*)ws; ws += (size_t)8192 * 2560 * 2;   // 41.9 MB
  bf16_t* VtB     = (bf16_t*)ws; ws += (size_t)4 * 256 * 2048 * 2;//  4.2 MB
  bf16_t* attnB   = (bf16_t*)ws;                                  // 33.5 MB

  // rope table aliases the attnB region (2 MB << 33.5 MB); attnB is written
  // only later by attn_kernel, after the table has been consumed.
  float2* ropeTab = (float2*)attnB;

  cvt_bf16_kernel<<<8192, 256, 0, stream>>>(hidden, hiddenB);
  transw_kernel<<<dim3(QKVN / 64, HID / 64), 256, 0, stream>>>(w_qkv, wqkvT, HID, QKVN);
  transw_kernel<<<dim3(HID / 64, HID / 64), 256, 0, stream>>>(w_o, woT, HID, HID);
  rope_table_kernel<<<SEQ, 128, 0, stream>>>(positions, ropeTab);

  gemm_bt_kernel<bf16_t><<<dim3(QKVN / 128, 64), 256, 0, stream>>>
      (hiddenB, wqkvT, qkvB, 8192, QKVN, HID);

  rope_kernel<<<dim3(BATCH * SEQ / 16, 9), 256, 0, stream>>>(ropeTab, qkvB);
  vtrans_kernel<<<dim3(SEQ / 64, HD / 64, BATCH), 256, 0, stream>>>(qkvB, VtB);

  attn_kernel<<<512, 256, 0, stream>>>(qkvB, VtB, attnB);

  gemm_bt_kernel<float><<<dim3(HID / 128, 64), 256, 0, stream>>>
      (attnB, woT, out, 8192, HID, HID);
}

// Round 3
// 474.156 us; speedup vs baseline: 1.6365x; 1.6365x over previous
//
#include <hip/hip_runtime.h>
#include <math.h>

constexpr int BATCH = 4;
constexpr int SEQ   = 2048;
constexpr int HID   = 2048;
constexpr int NHEAD = 8;
constexpr int HD    = 256;
constexpr int QKVN  = (NHEAD + 2) * HD;          // 2560
constexpr float SCL = 0.0625f;                   // 256^-0.5

typedef __bf16 bf16_t;
typedef __bf16 bf16x8 __attribute__((ext_vector_type(8)));
typedef float  f32x4  __attribute__((ext_vector_type(4)));

__device__ __forceinline__ f32x4 zero4() {
  f32x4 z; z[0] = 0.f; z[1] = 0.f; z[2] = 0.f; z[3] = 0.f; return z;
}

__device__ __forceinline__ f32x4 mfma16(bf16x8 a, bf16x8 b, f32x4 c) {
  return __builtin_amdgcn_mfma_f32_16x16x32_bf16(a, b, c, 0, 0, 0);
}

// async global->LDS, 16B per lane. lds must be wave-uniform base; HW adds lane*16.
__device__ __forceinline__ void gl2lds16(const void* g, void* lds) {
  typedef __attribute__((address_space(1))) void* gp_t;
  typedef __attribute__((address_space(3))) void* lp_t;
  __builtin_amdgcn_global_load_lds((gp_t)(size_t)g,
                                   (lp_t)(unsigned int)(size_t)lds, 16, 0, 0);
}

__device__ __forceinline__ float rmax16(float v) {
#pragma unroll
  for (int o = 1; o < 16; o <<= 1) v = fmaxf(v, __shfl_xor(v, o));
  return v;
}
__device__ __forceinline__ float rsum16(float v) {
#pragma unroll
  for (int o = 1; o < 16; o <<= 1) v += __shfl_xor(v, o);
  return v;
}

// ---------- fp32 -> bf16 bulk convert (8 elems/thread) ----------
__global__ __launch_bounds__(256)
void cvt_bf16_kernel(const float* __restrict__ in, bf16_t* __restrict__ out) {
  const int i = blockIdx.x * 256 + threadIdx.x;
  const float4 a = ((const float4*)in)[i * 2];
  const float4 b = ((const float4*)in)[i * 2 + 1];
  bf16x8 o;
  o[0] = (bf16_t)a.x; o[1] = (bf16_t)a.y; o[2] = (bf16_t)a.z; o[3] = (bf16_t)a.w;
  o[4] = (bf16_t)b.x; o[5] = (bf16_t)b.y; o[6] = (bf16_t)b.z; o[7] = (bf16_t)b.w;
  ((bf16x8*)out)[i] = o;
}

// ---------- w[K][N] fp32 -> wT[N][K] bf16, 64x64 tiles ----------
__global__ __launch_bounds__(256)
void transw_kernel(const float* __restrict__ w, bf16_t* __restrict__ wT, int K, int N) {
  __shared__ __align__(16) bf16_t tile[64][72];
  const int n0 = blockIdx.x * 64, k0 = blockIdx.y * 64;
  const int t = threadIdx.x, rr = t >> 3, c8 = (t & 7) * 8;
#pragma unroll
  for (int it = 0; it < 2; ++it) {
    const int r = rr + it * 32;
    const float4* p = (const float4*)(w + (size_t)(k0 + r) * N + n0 + c8);
    const float4 a = p[0], b = p[1];
    bf16x8 o;
    o[0] = (bf16_t)a.x; o[1] = (bf16_t)a.y; o[2] = (bf16_t)a.z; o[3] = (bf16_t)a.w;
    o[4] = (bf16_t)b.x; o[5] = (bf16_t)b.y; o[6] = (bf16_t)b.z; o[7] = (bf16_t)b.w;
    *(bf16x8*)&tile[r][c8] = o;
  }
  __syncthreads();
#pragma unroll
  for (int it = 0; it < 2; ++it) {
    const int rn = rr + it * 32;
    bf16x8 o;
#pragma unroll
    for (int j = 0; j < 8; ++j) o[j] = tile[c8 + j][rn];
    *(bf16x8*)&wT[(size_t)(n0 + rn) * K + k0 + c8] = o;
  }
}

// =====================================================================
// 256x256 8-phase GEMM (m201 template, plain HIP): C[M][N] = A * BT^T
// BM=BN=256, BK=64, 512 thr = 8 waves (2M x 4N), per-wave out 128x64.
// LDS 128 KiB: As/Bs[2 dbuf][2 half][128x64]. Frag ds_reads front-loaded
// in phases 1-2 of each 4-phase group; one half-tile stage per phase with
// 3-phase lead; counted vmcnt(4) at phases 4/8 only (never 0 mid-loop);
// raw s_barrier; setprio around MFMA clusters; XOR-(l15&7) chunk swizzle
// on both stage source and ds_read (same involution, rule #21).
// =====================================================================
#define BAR()   __builtin_amdgcn_s_barrier()
#define LGKM0() do { asm volatile("s_waitcnt lgkmcnt(0)" ::: "memory"); \
                     __builtin_amdgcn_sched_barrier(0); } while (0)
#define VMC(n)  asm volatile("s_waitcnt vmcnt(" #n ")" ::: "memory")

template <typename TC>
__global__ __launch_bounds__(512)
void gemm256_kernel(const bf16_t* __restrict__ A, const bf16_t* __restrict__ BT,
                    TC* __restrict__ C, int M, int N, int K) {
  __shared__ __align__(16) bf16_t As[2][2][128 * 64];   // [buf][half] 64 KB
  __shared__ __align__(16) bf16_t Bs[2][2][128 * 64];   // 64 KB

  const int tid = threadIdx.x;
  const int w = tid >> 6, lane = tid & 63;
  const int wr = w >> 2, wc = w & 3;
  const int quad = lane >> 4, l15 = lane & 15;
  const int bm = blockIdx.y * 256, bn = blockIdx.x * 256;

  // staging: thread tid covers 16B at linear byte (i*8192 + tid*16) of a half
  const int srow = tid >> 3;                    // 0..63 row within 64-row chunk
  const int sc16 = (tid & 7) ^ (srow & 7);      // pre-swizzled source chunk
  const bf16_t* Asrc = A  + (size_t)(bm + srow) * K + sc16 * 8;
  const bf16_t* Bsrc = BT + (size_t)(bn + srow) * K + sc16 * 8;

#define STAGE_A(t, h) do {                                                  \
    const bf16_t* _s = Asrc + (size_t)((h) * 128) * K + (t) * 64;           \
    gl2lds16(_s,                 &As[(t) & 1][h][w * 512]);                 \
    gl2lds16(_s + (size_t)64 * K, &As[(t) & 1][h][4096 + w * 512]);         \
  } while (0)
#define STAGE_B(t, h) do {                                                  \
    const bf16_t* _s = Bsrc + (size_t)((h) * 128) * K + (t) * 64;           \
    gl2lds16(_s,                 &Bs[(t) & 1][h][w * 512]);                 \
    gl2lds16(_s + (size_t)64 * K, &Bs[(t) & 1][h][4096 + w * 512]);         \
  } while (0)

  // fragment read offsets (elements). chunk(k2=0)=c0, chunk(k2=1)=c0^32.
  const int c0  = ((quad ^ (l15 & 7)) << 3);
  const int aro = l15 * 64;                     // + mt*1024
  const int bh  = wc >> 1;
  const int bro = ((wc & 1) * 64 + l15) * 64;   // + nt*1024

  f32x4 acc[8][4];
#pragma unroll
  for (int mt = 0; mt < 8; ++mt)
#pragma unroll
    for (int nt = 0; nt < 4; ++nt) acc[mt][nt] = zero4();

  bf16x8 bfr[4][2], a01[2][2], a2[6][2];

#define LD_B(b) do { _Pragma("unroll")                                      \
    for (int nt = 0; nt < 4; ++nt) {                                        \
      bfr[nt][0] = *(const bf16x8*)&Bs[b][bh][bro + nt * 1024 + c0];        \
      bfr[nt][1] = *(const bf16x8*)&Bs[b][bh][bro + nt * 1024 + (c0 ^ 32)]; \
    } } while (0)
#define LD_A01(b) do { _Pragma("unroll")                                    \
    for (int mt = 0; mt < 2; ++mt) {                                        \
      a01[mt][0] = *(const bf16x8*)&As[b][wr][aro + mt * 1024 + c0];        \
      a01[mt][1] = *(const bf16x8*)&As[b][wr][aro + mt * 1024 + (c0 ^ 32)]; \
    } } while (0)
#define LD_A2(b) do { _Pragma("unroll")                                     \
    for (int i = 0; i < 6; ++i) {                                           \
      a2[i][0] = *(const bf16x8*)&As[b][wr][aro + (i + 2) * 1024 + c0];     \
      a2[i][1] = *(const bf16x8*)&As[b][wr][aro + (i + 2) * 1024 + (c0^32)];\
    } } while (0)
#define MFMA8(A0, A1, mb) do {                                              \
    __builtin_amdgcn_s_setprio(1);                                          \
    _Pragma("unroll")                                                       \
    for (int nt = 0; nt < 4; ++nt) {                                        \
      acc[(mb)][nt]     = mfma16((A0)[0], bfr[nt][0], acc[(mb)][nt]);       \
      acc[(mb)][nt]     = mfma16((A0)[1], bfr[nt][1], acc[(mb)][nt]);       \
      acc[(mb)+1][nt]   = mfma16((A1)[0], bfr[nt][0], acc[(mb)+1][nt]);     \
      acc[(mb)+1][nt]   = mfma16((A1)[1], bfr[nt][1], acc[(mb)+1][nt]);     \
    }                                                                       \
    __builtin_amdgcn_s_setprio(0);                                          \
  } while (0)

  const int NITER = K >> 7;                     // K/128 (two BK=64 tiles/iter)

  // ---- prologue: t0 fully + t1 A-halves; drain t0, keep t1.A in flight ----
  STAGE_A(0, 0); STAGE_A(0, 1); STAGE_B(0, 0); STAGE_B(0, 1);
  STAGE_A(1, 0); STAGE_A(1, 1);
  VMC(4);
  BAR();

  for (int u = 0; u < NITER; ++u) {
    const bool last = (u == NITER - 1);
    const int t1 = 2 * u + 1, t2 = 2 * u + 2, t3 = 2 * u + 3;

    // ===== P1: reads buf0 (B all + A m0,m1); stage t1.Bh0 =====
    LD_B(0); LD_A01(0);
    STAGE_B(t1, 0);
    BAR(); LGKM0();
    MFMA8(a01[0], a01[1], 0);
    BAR();
    // ===== P2: reads buf0 (A m2..7); stage t1.Bh1 =====
    LD_A2(0);
    STAGE_B(t1, 1);
    BAR(); LGKM0();
    MFMA8(a2[0], a2[1], 2);
    BAR();
    // ===== P3: stage t2.Ah0 =====
    if (!last) STAGE_A(t2, 0);
    BAR();
    MFMA8(a2[2], a2[3], 4);
    BAR();
    // ===== P4: stage t2.Ah1; drain so t1 is fully resident =====
    if (!last) { STAGE_A(t2, 1); VMC(4); } else { VMC(0); }
    BAR();
    MFMA8(a2[4], a2[5], 6);
    BAR();
    // ===== P5: reads buf1 (B all + A m0,m1); stage t2.Bh0 =====
    LD_B(1); LD_A01(1);
    if (!last) STAGE_B(t2, 0);
    BAR(); LGKM0();
    MFMA8(a01[0], a01[1], 0);
    BAR();
    // ===== P6: reads buf1 (A m2..7); stage t2.Bh1 =====
    LD_A2(1);
    if (!last) STAGE_B(t2, 1);
    BAR(); LGKM0();
    MFMA8(a2[0], a2[1], 2);
    BAR();
    // ===== P7: stage t3.Ah0 =====
    if (!last) STAGE_A(t3, 0);
    BAR();
    MFMA8(a2[2], a2[3], 4);
    BAR();
    // ===== P8: stage t3.Ah1; drain so t2 is fully resident =====
    if (!last) { STAGE_A(t3, 1); VMC(4); }
    BAR();
    MFMA8(a2[4], a2[5], 6);
    BAR();
  }

  // ---- epilogue: C write ----
#pragma unroll
  for (int mt = 0; mt < 8; ++mt)
#pragma unroll
    for (int nt = 0; nt < 4; ++nt)
#pragma unroll
      for (int r = 0; r < 4; ++r) {
        const int row = bm + wr * 128 + mt * 16 + quad * 4 + r;
        const int col = bn + wc * 64 + nt * 16 + l15;
        C[(size_t)row * N + col] = (TC)acc[mt][nt][r];
      }
#undef STAGE_A
#undef STAGE_B
#undef LD_B
#undef LD_A01
#undef LD_A2
#undef MFMA8
}

// ---------- RoPE cos/sin table: tab[s][i] = (cos, sin) ----------
__global__ __launch_bounds__(128)
void rope_table_kernel(const int* __restrict__ pos, float2* __restrict__ tab) {
  const int s = blockIdx.x, i = threadIdx.x;
  const float inv_freq = powf(10000.0f, -(float)i / 128.0f);
  const float ang = (float)pos[s] * inv_freq;
  float sn, cs;
  sincosf(ang, &sn, &cs);
  tab[s * 128 + i] = make_float2(cs, sn);
}

// ---------- RoPE apply, table-driven, bf16x8 vectorized ----------
__global__ __launch_bounds__(256)
void rope_kernel(const float2* __restrict__ tab, bf16_t* __restrict__ qkv) {
  const int bs = blockIdx.x * 16 + (threadIdx.x >> 4);
  const int h  = blockIdx.y;
  const int i0 = (threadIdx.x & 15) * 8;
  const int s  = bs & (SEQ - 1);
  const size_t base = (size_t)bs * QKVN + (size_t)h * HD;
  bf16x8 a = *(const bf16x8*)&qkv[base + i0];
  bf16x8 b = *(const bf16x8*)&qkv[base + 128 + i0];
  bf16x8 oa, ob;
#pragma unroll
  for (int j = 0; j < 8; ++j) {
    const float2 t = tab[s * 128 + i0 + j];
    const float x1 = (float)a[j], x2 = (float)b[j];
    oa[j] = (bf16_t)(x1 * t.x - x2 * t.y);
    ob[j] = (bf16_t)(x2 * t.x + x1 * t.y);
  }
  *(bf16x8*)&qkv[base + i0]       = oa;
  *(bf16x8*)&qkv[base + 128 + i0] = ob;
}

// ---------- V transpose: qkv v-part [s][d] -> Vt[b][d][s] ----------
__global__ __launch_bounds__(256)
void vtrans_kernel(const bf16_t* __restrict__ qkv, bf16_t* __restrict__ Vt) {
  __shared__ __align__(16) bf16_t tile[64][72];
  const int s0 = blockIdx.x * 64, d0 = blockIdx.y * 64, b = blockIdx.z;
  const int t = threadIdx.x, rr = t >> 3, c8 = (t & 7) * 8;
#pragma unroll
  for (int it = 0; it < 2; ++it) {
    const int r = rr + it * 32;
    *(bf16x8*)&tile[r][c8] =
        *(const bf16x8*)&qkv[(size_t)(b * SEQ + s0 + r) * QKVN + 2304 + d0 + c8];
  }
  __syncthreads();
#pragma unroll
  for (int it = 0; it < 2; ++it) {
    const int dd = rr + it * 32;
    bf16x8 o;
#pragma unroll
    for (int j = 0; j < 8; ++j) o[j] = tile[c8 + j][dd];
    *(bf16x8*)&Vt[(size_t)(b * HD + d0 + dd) * SEQ + s0 + c8] = o;
  }
}

// ---------- flash attention (round-1 known-good version, 138.5 us) ----------
// Block: 512 threads = 8 waves, wave w = head w. All waves share one K/V tile.
// Complementary q-tile pair (qt, 127-qt) per block -> uniform ~33 iterations.
// 2-phase pipeline: stage tile kt+1 into buf^1 while computing tile kt.
__global__ __launch_bounds__(512)
void attn_kernel(const bf16_t* __restrict__ qkv, const bf16_t* __restrict__ Vt,
                 bf16_t* __restrict__ O) {
  __shared__ __align__(16) bf16_t Ks[2][64 * 256];
  __shared__ __align__(16) bf16_t Vts[2][256 * 64];
  __shared__ __align__(16) bf16_t Pl[8][16][72];

  const int tid = threadIdx.x, w = tid >> 6, lane = tid & 63;
  const int quad = lane >> 4, l15 = lane & 15;
  const int b = blockIdx.x >> 6;
  const int qtR = blockIdx.x & 63;
  const int h = w;

  const int krow_base = w * 2 + (lane >> 5);
  const int kcol = lane & 31;
  const int vrow_base = w * 8 + (lane >> 3);
  const int vcol = lane & 7;

  const bf16_t* kbase0 = qkv + (size_t)(b * SEQ) * QKVN + 2048;
  const bf16_t* vbase0 = Vt + (size_t)b * HD * SEQ;

  auto stage = [&](int kt, int buf) {
    const bf16_t* kbase = kbase0 + (size_t)(kt * 64) * QKVN;
#pragma unroll
    for (int i = 0; i < 4; ++i) {
      const int r = i * 16 + krow_base;
      gl2lds16(kbase + (size_t)r * QKVN + ((kcol ^ (r & 31)) << 3),
               &Ks[buf][(i * 512 + w * 64) * 8]);
    }
    const bf16_t* vbase = vbase0 + kt * 64;
#pragma unroll
    for (int i = 0; i < 4; ++i) {
      const int r = i * 64 + vrow_base;
      gl2lds16(vbase + (size_t)r * SEQ + ((vcol ^ (r & 7)) << 3),
               &Vts[buf][(i * 512 + w * 64) * 8]);
    }
  };

  for (int phase = 0; phase < 2; ++phase) {
    const int qt = phase ? (127 - qtR) : qtR;
    const int q0 = qt * 16;

    bf16x8 qf[8];
    const bf16_t* qp =
        qkv + (size_t)(b * SEQ + q0 + l15) * QKVN + (size_t)h * HD + quad * 8;
#pragma unroll
    for (int ks = 0; ks < 8; ++ks) qf[ks] = *(const bf16x8*)(qp + ks * 32);

    float mrun[4], lrun[4];
    f32x4 of[16];
#pragma unroll
    for (int r = 0; r < 4; ++r) { mrun[r] = -3e38f; lrun[r] = 0.f; }
#pragma unroll
    for (int dt = 0; dt < 16; ++dt) of[dt] = zero4();

    const int ntiles = q0 / 64 + 1;
    int cur = 0;
    stage(0, 0);
    __syncthreads();

    for (int kt = 0; kt < ntiles; ++kt) {
      if (kt + 1 < ntiles) stage(kt + 1, cur ^ 1);

      const bf16_t* ksb = Ks[cur];
      const bf16_t* vsb = Vts[cur];

      f32x4 sf[4];
#pragma unroll
      for (int nt = 0; nt < 4; ++nt) {
        f32x4 acc = zero4();
        const int row = nt * 16 + l15;
#pragma unroll
        for (int ks = 0; ks < 8; ++ks) {
          const int j = ks * 4 + quad;
          const bf16x8 kf = *(const bf16x8*)&ksb[row * 256 + ((j ^ (row & 31)) << 3)];
          acc = mfma16(qf[ks], kf, acc);
        }
        sf[nt] = acc;
      }

      const bool lastTile = (kt == ntiles - 1);
      float mx[4];
#pragma unroll
      for (int r = 0; r < 4; ++r) {
        const int qg = q0 + quad * 4 + r;
        float v = -3e38f;
#pragma unroll
        for (int nt = 0; nt < 4; ++nt) {
          float s = sf[nt][r] * SCL;
          if (lastTile) {
            const int kg = kt * 64 + nt * 16 + l15;
            if (kg > qg) s = -3e38f;
          }
          sf[nt][r] = s;
          v = fmaxf(v, s);
        }
        mx[r] = rmax16(v);
      }

      float g = 0.f;
#pragma unroll
      for (int r = 0; r < 4; ++r) g = fmaxf(g, mx[r] - mrun[r]);
      const bool resc = !__all(g <= 8.0f);
      f32x4 av;
      if (resc) {
#pragma unroll
        for (int r = 0; r < 4; ++r) {
          const float mn = fmaxf(mrun[r], mx[r]);
          av[r] = __expf(mrun[r] - mn);
          mrun[r] = mn;
          lrun[r] *= av[r];
        }
      }

#pragma unroll
      for (int r = 0; r < 4; ++r) {
        float sum = 0.f;
#pragma unroll
        for (int nt = 0; nt < 4; ++nt) {
          const float pv = __expf(sf[nt][r] - mrun[r]);
          Pl[w][quad * 4 + r][nt * 16 + l15] = (bf16_t)pv;
          sum += pv;
        }
        lrun[r] += rsum16(sum);
      }
      if (resc) {
#pragma unroll
        for (int dt = 0; dt < 16; ++dt) of[dt] *= av;
      }
      __asm__ volatile("s_waitcnt lgkmcnt(0)" ::: "memory");

      bf16x8 pa[2];
#pragma unroll
      for (int k2 = 0; k2 < 2; ++k2)
        pa[k2] = *(const bf16x8*)&Pl[w][l15][k2 * 32 + quad * 8];
#pragma unroll
      for (int dt = 0; dt < 16; ++dt) {
        const int row = dt * 16 + l15;
#pragma unroll
        for (int k2 = 0; k2 < 2; ++k2) {
          const int j = k2 * 4 + quad;
          const bf16x8 vf = *(const bf16x8*)&vsb[row * 64 + ((j ^ (row & 7)) << 3)];
          of[dt] = mfma16(pa[k2], vf, of[dt]);
        }
      }

      __syncthreads();
      cur ^= 1;
    }

    f32x4 iv;
#pragma unroll
    for (int r = 0; r < 4; ++r) iv[r] = 1.0f / lrun[r];
#pragma unroll
    for (int dt = 0; dt < 16; ++dt) {
      const f32x4 o = of[dt] * iv;
#pragma unroll
      for (int r = 0; r < 4; ++r)
        O[(size_t)(b * SEQ + q0 + quad * 4 + r) * HID + (size_t)h * HD + dt * 16 + l15] =
            (bf16_t)o[r];
    }
  }
}

// ---------- launch ----------
extern "C" void kernel_launch(void* const* d_in, const int* in_sizes, int n_in,
                              void* d_out, int out_size, void* d_ws, size_t ws_size,
                              hipStream_t stream) {
  const float* hidden  = (const float*)d_in[0];
  const int* positions = (const int*)d_in[1];
  const float* w_qkv   = (const float*)d_in[2];
  const float* w_o     = (const float*)d_in[3];
  float* out           = (float*)d_out;

  char* ws = (char*)d_ws;
  bf16_t* hiddenB = (bf16_t*)ws; ws += (size_t)8192 * 2048 * 2;   // 33.5 MB
  bf16_t* wqkvT   = (bf16_t*)ws; ws += (size_t)2560 * 2048 * 2;   // 10.5 MB
  bf16_t* woT     = (bf16_t*)ws; ws += (size_t)2048 * 2048 * 2;   //  8.4 MB
  bf16_t* qkvB    = (bf16_t*)ws; ws += (size_t)8192 * 2560 * 2;   // 41.9 MB
  bf16_t* VtB     = (bf16_t*)ws; ws += (size_t)4 * 256 * 2048 * 2;//  4.2 MB
  bf16_t* attnB   = (bf16_t*)ws;                                  // 33.5 MB

  // rope table aliases the attnB region (2 MB << 33.5 MB); consumed before
  // attn_kernel writes attnB.
  float2* ropeTab = (float2*)attnB;

  cvt_bf16_kernel<<<8192, 256, 0, stream>>>(hidden, hiddenB);
  transw_kernel<<<dim3(QKVN / 64, HID / 64), 256, 0, stream>>>(w_qkv, wqkvT, HID, QKVN);
  transw_kernel<<<dim3(HID / 64, HID / 64), 256, 0, stream>>>(w_o, woT, HID, HID);
  rope_table_kernel<<<SEQ, 128, 0, stream>>>(positions, ropeTab);

  gemm256_kernel<bf16_t><<<dim3(QKVN / 256, 8192 / 256), 512, 0, stream>>>
      (hiddenB, wqkvT, qkvB, 8192, QKVN, HID);

  rope_kernel<<<dim3(BATCH * SEQ / 16, 9), 256, 0, stream>>>(ropeTab, qkvB);
  vtrans_kernel<<<dim3(SEQ / 64, HD / 64, BATCH), 256, 0, stream>>>(qkvB, VtB);

  attn_kernel<<<256, 512, 0, stream>>>(qkvB, VtB, attnB);

  gemm256_kernel<float><<<dim3(HID / 256, 8192 / 256), 512, 0, stream>>>
      (attnB, woT, out, 8192, HID, HID);
}